// Round 12
// baseline (360.031 us; speedup 1.0000x reference)
//
#include <hip/hip_runtime.h>
#include <hip/hip_bf16.h>

// LocalResnetPointnet v12: r11 + software-pipelined tile staging (register
// prefetch one tile ahead), LDS stride 140 for C-layout tiles (bank-conflict-
// free C writes), packed b64 fc_pos writes.

#define G_ALL 131072   // B*T
#define HD    128
#define NBINS 16384

typedef __attribute__((ext_vector_type(8))) short short8;
typedef __attribute__((ext_vector_type(4))) short short4v;
typedef __attribute__((ext_vector_type(4))) float f32x4;

#define MFMA16(a, b, c) __builtin_amdgcn_mfma_f32_16x16x32_bf16(a, b, c, 0, 0, 0)

__device__ __forceinline__ float bf16_to_f32(unsigned short u) {
  union { unsigned int u; float f; } v; v.u = ((unsigned int)u) << 16; return v.f;
}
__device__ __forceinline__ unsigned short f32_to_bf16(float f) {
  union { float f; unsigned int u; } v; v.f = f;
  unsigned int u = v.u;
  u += 0x7fffu + ((u >> 16) & 1u);   // RNE (no NaNs in this workload)
  return (unsigned short)(u >> 16);
}
// order-preserving float -> uint key for atomicMax
__device__ __forceinline__ unsigned int f32_key(float f) {
  union { float f; unsigned int u; } v; v.f = f;
  return (v.u & 0x80000000u) ? ~v.u : (v.u | 0x80000000u);
}
__device__ __forceinline__ float key_f32(unsigned int k) {
  union { unsigned int u; float f; } v;
  v.u = (k & 0x80000000u) ? (k & 0x7fffffffu) : ~k;
  return v.f;
}
__device__ __forceinline__ int bin_of(float p0, float p2) {
  float x = p0 / 1.101f + 0.5f;
  x = fminf(fmaxf(x, 0.0f), 1.0f - 1e-6f);
  int xi = (int)(x * 128.0f);
  float z = p2 / 1.101f + 0.5f;
  z = fminf(fmaxf(z, 0.0f), 1.0f - 1e-6f);
  int zi = (int)(z * 128.0f);
  return xi + 128 * zi;
}
__device__ __forceinline__ short8 relu8(short8 a) {
  short8 r;
#pragma unroll
  for (int e = 0; e < 8; e++) r[e] = a[e] < 0 ? (short)0 : a[e];
  return r;
}

// ---------------- prep: zero hist/pool; block 0 computes Sp/bsp ------------
__global__ __launch_bounds__(128) void prep_kernel(
    const float* __restrict__ fcw, const float* __restrict__ fcb,
    const float* __restrict__ ws0, float* __restrict__ Sp,
    float* __restrict__ bsp, unsigned int* __restrict__ pool,
    int* __restrict__ hist) {
  int t = blockIdx.x * 128 + threadIdx.x;  // 16384 threads
  hist[t * 2] = 0;
  hist[t * 2 + 1] = 0;
  if (t < 1024) pool[t] = 0u;
  if (blockIdx.x == 0) {
    int j = threadIdx.x;
    for (int d = 0; d < 3; d++) {
      float s = 0.f;
      for (int ch = 0; ch < 256; ch++)
        s = fmaf(fcw[d * 256 + ch], ws0[ch * HD + j], s);
      Sp[d * HD + j] = s;
    }
    float s = 0.f;
    for (int ch = 0; ch < 256; ch++)
      s = fmaf(fcb[ch], ws0[ch * HD + j], s);
    bsp[j] = s;
  }
}

// ---------------- merged: weight transpose/cast + bin histogram ------------
__global__ __launch_bounds__(256) void wi_kernel(
    const float* __restrict__ w0, const float* __restrict__ w1,
    const float* __restrict__ ws, const float* __restrict__ p,
    unsigned short* __restrict__ B0t, unsigned short* __restrict__ W0t,
    unsigned short* __restrict__ W1t, unsigned short* __restrict__ WSt,
    int* __restrict__ hist) {
  int gid = blockIdx.x * 256 + threadIdx.x;
  if (gid >= 245760) {                     // index part: 131072 threads
    int g = gid - 245760;
    int b = g >> 16;
    int idx = bin_of(p[3 * (size_t)g], p[3 * (size_t)g + 2]);
    atomicAdd(&hist[b * NBINS + idx], 1);
    return;
  }
  float v;
  unsigned short* dstp;
  int dst;
  if (gid < 32768) {                       // B0t: [n][k] from w0[0] (256x128)
    int n = gid >> 8, k = gid & 255;
    v = w0[k * 128 + n];
    dstp = B0t; dst = gid;
  } else if (gid < 98304) {                // W0t stages 1..4, rows 0..127
    int i = gid - 32768; int s = i >> 14; int n = (i >> 7) & 127; int k = i & 127;
    v = w0[(size_t)((s + 1) * 256 + k) * 128 + n];
    dstp = W0t; dst = i;
  } else if (gid < 180224) {               // W1t stages 0..4
    int i = gid - 98304; int s = i >> 14; int n = (i >> 7) & 127; int k = i & 127;
    v = w1[(size_t)(s * 128 + k) * 128 + n];
    dstp = W1t; dst = i;
  } else {                                 // WSt stages 1..4, rows 0..127
    int i = gid - 180224; int s = i >> 14; int n = (i >> 7) & 127; int k = i & 127;
    v = ws[(size_t)((s + 1) * 256 + k) * 128 + n];
    dstp = WSt; dst = i;
  }
  dstp[dst] = f32_to_bf16(v);
}

__global__ __launch_bounds__(1024) void scan_kernel(int* __restrict__ hist,
                                                    int* __restrict__ offsets) {
  __shared__ int sd[1024];
  int t = threadIdx.x;
  int vals[32];
  int s = 0;
#pragma unroll
  for (int i = 0; i < 32; i++) { vals[i] = hist[t * 32 + i]; s += vals[i]; }
  sd[t] = s;
  __syncthreads();
  for (int d = 1; d < 1024; d <<= 1) {
    int v = (t >= d) ? sd[t - d] : 0;
    __syncthreads();
    sd[t] += v;
    __syncthreads();
  }
  int run = sd[t] - s;  // exclusive prefix
#pragma unroll
  for (int i = 0; i < 32; i++) {
    offsets[t * 32 + i] = run;
    hist[t * 32 + i] = run;  // cursor copy (in-place)
    run += vals[i];
  }
  if (t == 1023) offsets[32768] = run;  // sentinel = G_ALL
}

__global__ __launch_bounds__(256) void fill_kernel(const float* __restrict__ p,
                                                   int* __restrict__ cursor,
                                                   int* __restrict__ rank) {
  int g = blockIdx.x * 256 + threadIdx.x;
  int b = g >> 16;
  int idx = bin_of(p[3 * (size_t)g], p[3 * (size_t)g + 2]);
  int pos = atomicAdd(&cursor[b * NBINS + idx], 1);
  rank[g] = pos;
}

// gather + mean over SORTED rows: block = 64 bins, rows sequential, no
// indirection. Register accumulate -> LDS transpose -> coalesced stores.
__global__ __launch_bounds__(256) void gather_kernel(
    const unsigned short* __restrict__ cS, const int* __restrict__ offsets,
    float* __restrict__ out) {
  __shared__ float acc[129 * 65];  // [ch 0..127 | cnt row 128][bin 0..63]
  const int tid = threadIdx.x;
  const int wave = tid >> 6, lane = tid & 63;
  const int B0 = blockIdx.x * 64;          // global bin base (0..32767)
  const int b = B0 >> 14;

  for (int bi = 0; bi < 16; bi++) {
    const int binL = wave * 16 + bi;
    const int B = B0 + binL;
    const int st = offsets[B], en = offsets[B + 1];
    float a0 = 0.f, a1 = 0.f;
    int k = st;
    for (; k + 2 <= en; k += 2) {
      unsigned int u0 = *(const unsigned int*)(cS + (size_t)k * HD + lane * 2);
      unsigned int u1 = *(const unsigned int*)(cS + (size_t)(k + 1) * HD + lane * 2);
      a0 += bf16_to_f32((unsigned short)(u0 & 0xffffu));
      a1 += bf16_to_f32((unsigned short)(u0 >> 16));
      a0 += bf16_to_f32((unsigned short)(u1 & 0xffffu));
      a1 += bf16_to_f32((unsigned short)(u1 >> 16));
    }
    if (k < en) {
      unsigned int u = *(const unsigned int*)(cS + (size_t)k * HD + lane * 2);
      a0 += bf16_to_f32((unsigned short)(u & 0xffffu));
      a1 += bf16_to_f32((unsigned short)(u >> 16));
    }
    acc[(2 * lane) * 65 + binL] = a0;
    acc[(2 * lane + 1) * 65 + binL] = a1;
    if (lane == 0) acc[128 * 65 + binL] = (float)(en - st);
  }
  __syncthreads();

  const size_t outBase = (size_t)b * HD * NBINS + (size_t)(B0 & (NBINS - 1));
  const float cnt = fmaxf(acc[128 * 65 + lane], 1.0f);
#pragma unroll
  for (int c2 = 0; c2 < 32; c2++) {
    int ch = wave * 32 + c2;
    out[outBase + (size_t)ch * NBINS + lane] = acc[ch * 65 + lane] / cnt;
  }
}

// ---------------- stage 0: fc_pos + block0 (weight-stationary MFMA) --------
// 8 waves; wave = nt (16 output ch). 512 blocks x 4 tiles of 64 rows.
// p prefetched one tile ahead; out tile at stride 140 in x0t region.
__global__ __launch_bounds__(512, 4) void stage0_kernel(
    const float* __restrict__ p, const float* __restrict__ fcw,
    const float* __restrict__ fcb,
    const unsigned short* __restrict__ B0t,
    const unsigned short* __restrict__ W1t,
    const float* __restrict__ b0, const float* __restrict__ b1,
    const float* __restrict__ Sp, const float* __restrict__ bsp,
    unsigned short* __restrict__ hout, unsigned int* __restrict__ pool) {
  __shared__ float fcL[1024];                // fcw (768) + fcb (256)
  __shared__ float ptL[64 * 5];              // stride 5: conflict-free q-reads
  __shared__ unsigned short x0t[64 * 264];   // K=256 relu tile; out tile (stride 140)
  __shared__ unsigned short m2[64 * 140];
  const int tid = threadIdx.x;
  const int lane = tid & 63;
  const int q = lane >> 4, l15 = lane & 15;
  const int nt = tid >> 6;                   // wave id = output-ch tile
  const int b = blockIdx.x >> 8;
  const int wrow = nt * 16 + l15;
  const int row8 = tid >> 3, c4 = (tid & 7) * 4;

  // weights -> registers (once per kernel): 8 + 4 short8 = 48 VGPRs
  short8 b0w[8], w1w[4];
#pragma unroll
  for (int kc = 0; kc < 8; kc++)
    b0w[kc] = *(const short8*)(B0t + (size_t)wrow * 256 + kc * 32 + q * 8);
#pragma unroll
  for (int kc = 0; kc < 4; kc++)
    w1w[kc] = *(const short8*)(W1t + (size_t)wrow * 128 + kc * 32 + q * 8);
  const float bias1 = b0[wrow];
  const float bias2 = bsp[wrow] + b1[wrow];
  const float sp0 = Sp[wrow], sp1 = Sp[128 + wrow], sp2 = Sp[256 + wrow];

  for (int k = tid; k < 1024; k += 512)
    fcL[k] = (k < 768) ? fcw[k] : fcb[k - 768];

  // prefetch tile 0
  float pn0, pn1, pn2, pl = 0.f;
  {
    const int rb = blockIdx.x * 256;
    const float* pr = p + (size_t)(rb + row8) * 3;
    pn0 = pr[0]; pn1 = pr[1]; pn2 = pr[2];
    if (tid < 192) pl = p[(size_t)rb * 3 + tid];
  }

  for (int it = 0; it < 4; it++) {
    const int rowBase = blockIdx.x * 256 + it * 64;
    __syncthreads();  // #1: fcL ready (it0) / prev out-store + ptL reads done
    if (tid < 192) ptL[(tid / 3) * 5 + (tid % 3)] = pl;
    // fc_pos from prefetched registers: 8 groups of 4 consecutive channels
#pragma unroll
    for (int cc = 0; cc < 8; cc++) {
      int chb = c4 + cc * 32;
      short4v v;
#pragma unroll
      for (int j = 0; j < 4; j++) {
        int ch = chb + j;
        float x = fcL[768 + ch] + pn0 * fcL[ch] + pn1 * fcL[256 + ch] +
                  pn2 * fcL[512 + ch];
        v[j] = (short)f32_to_bf16(fmaxf(x, 0.f));
      }
      *(short4v*)(&x0t[row8 * 264 + chb]) = v;
    }
    if (it < 3) {  // prefetch next tile's p
      const int rb = rowBase + 64;
      const float* pr = p + (size_t)(rb + row8) * 3;
      pn0 = pr[0]; pn1 = pr[1]; pn2 = pr[2];
      if (tid < 192) pl = p[(size_t)rb * 3 + tid];
    }
    __syncthreads();  // #2: x0t + ptL ready
    // phase 1: net = relu(x0) @ W0[0] + b0[0]  (K=256)
    f32x4 C1[4];
#pragma unroll
    for (int s = 0; s < 4; s++) C1[s] = (f32x4){bias1, bias1, bias1, bias1};
#pragma unroll
    for (int kc = 0; kc < 8; kc++) {
#pragma unroll
      for (int s = 0; s < 4; s++) {
        short8 Ar = *(const short8*)(&x0t[(s * 16 + l15) * 264 + kc * 32 + q * 8]);
        C1[s] = MFMA16(Ar, b0w[kc], C1[s]);
      }
    }
#pragma unroll
    for (int s = 0; s < 4; s++)
#pragma unroll
      for (int r = 0; r < 4; r++)
        m2[(s * 16 + q * 4 + r) * 140 + nt * 16 + l15] =
            f32_to_bf16(fmaxf(C1[s][r], 0.f));
    __syncthreads();  // #3: m2 ready; x0t phase-1 reads done -> out region
    // phase 2: h = m2 @ W1[0] + (p @ Sp + bsp + b1[0])
    f32x4 C2[4];
#pragma unroll
    for (int s = 0; s < 4; s++)
#pragma unroll
      for (int r = 0; r < 4; r++) {
        int row = s * 16 + q * 4 + r;
        C2[s][r] = bias2 + ptL[row * 5] * sp0 + ptL[row * 5 + 1] * sp1 +
                   ptL[row * 5 + 2] * sp2;
      }
#pragma unroll
    for (int kc = 0; kc < 4; kc++) {
#pragma unroll
      for (int s = 0; s < 4; s++) {
        short8 Am = *(const short8*)(&m2[(s * 16 + l15) * 140 + kc * 32 + q * 8]);
        C2[s] = MFMA16(Am, w1w[kc], C2[s]);
      }
    }
#pragma unroll
    for (int s = 0; s < 4; s++)
#pragma unroll
      for (int r = 0; r < 4; r++)
        x0t[(s * 16 + q * 4 + r) * 140 + nt * 16 + l15] = f32_to_bf16(C2[s][r]);
    {
      float m = -1e30f;
#pragma unroll
      for (int s = 0; s < 4; s++)
#pragma unroll
        for (int r = 0; r < 4; r++) m = fmaxf(m, C2[s][r]);
      m = fmaxf(m, __shfl_xor(m, 16, 64));
      m = fmaxf(m, __shfl_xor(m, 32, 64));
      if (lane < 16) atomicMax(&pool[b * 128 + nt * 16 + lane], f32_key(m));
    }
    __syncthreads();  // #4: out tile ready
    {
      int cs = (tid & 7) * 16;
      short8 v0 = *(const short8*)(&x0t[row8 * 140 + cs]);
      short8 v1 = *(const short8*)(&x0t[row8 * 140 + cs + 8]);
      *(short8*)(hout + (size_t)(rowBase + row8) * 128 + cs) = v0;
      *(short8*)(hout + (size_t)(rowBase + row8) * 128 + cs + 8) = v1;
    }
  }
}

// ---------------- stages 1..4 (weight-stationary, pipelined staging) -------
// 8 waves; wave = nt. 512 blocks x 4 tiles of 64 rows. WS fused in phase 1.
// H tile prefetched one tile ahead into registers. Out tile reuses At.
__global__ __launch_bounds__(512, 4) void stageN_kernel(
    const unsigned short* __restrict__ hin, unsigned short* __restrict__ hout,
    const unsigned short* __restrict__ W0t,
    const unsigned short* __restrict__ W1t,
    const unsigned short* __restrict__ WSt,
    const float* __restrict__ b0e, const float* __restrict__ bse,
    unsigned int* __restrict__ pool, int doPool,
    const int* __restrict__ rank, int useRank) {
  __shared__ unsigned short At[64 * 140];   // H tile; reused as output tile
  __shared__ unsigned short m2[64 * 140];   // relu(net)
  const int tid = threadIdx.x;
  const int lane = tid & 63;
  const int q = lane >> 4, l15 = lane & 15;
  const int nt = tid >> 6;
  const int b = blockIdx.x >> 8;
  const int wrow = nt * 16 + l15;

  // 12 short8 = 48 VGPRs of weights
  short8 w0w[4], w1w[4], wsw[4];
#pragma unroll
  for (int kc = 0; kc < 4; kc++) {
    w0w[kc] = *(const short8*)(W0t + (size_t)wrow * 128 + kc * 32 + q * 8);
    w1w[kc] = *(const short8*)(W1t + (size_t)wrow * 128 + kc * 32 + q * 8);
    wsw[kc] = *(const short8*)(WSt + (size_t)wrow * 128 + kc * 32 + q * 8);
  }
  const float bias1 = b0e[b * 128 + wrow];
  const float bias2 = bse[b * 128 + wrow];
  const int r8 = tid >> 3, cs8 = (tid & 7) * 16;

  // prefetch tile 0
  short8 n0, n1;
  {
    const size_t gb = ((size_t)blockIdx.x * 256 + r8) * 128 + cs8;
    n0 = *(const short8*)(hin + gb);
    n1 = *(const short8*)(hin + gb + 8);
  }

  for (int it = 0; it < 4; it++) {
    const int rowBase = blockIdx.x * 256 + it * 64;
    __syncthreads();  // #1: prev out-store LDS reads done -> At writable
    *(short8*)(&At[r8 * 140 + cs8]) = n0;
    *(short8*)(&At[r8 * 140 + cs8 + 8]) = n1;
    if (it < 3) {  // prefetch next tile (latency hidden behind this tile)
      const size_t gb = ((size_t)(rowBase + 64) + r8) * 128 + cs8;
      n0 = *(const short8*)(hin + gb);
      n1 = *(const short8*)(hin + gb + 8);
    }
    __syncthreads();  // #2: At ready
    // phase 1: C1 = relu(H)@W0 + b0e ; C2 = H@WS + bse (shortcut fused)
    f32x4 C1[4], C2[4];
#pragma unroll
    for (int s = 0; s < 4; s++) {
      C1[s] = (f32x4){bias1, bias1, bias1, bias1};
      C2[s] = (f32x4){bias2, bias2, bias2, bias2};
    }
#pragma unroll
    for (int kc = 0; kc < 4; kc++) {
#pragma unroll
      for (int s = 0; s < 4; s++) {
        short8 Ah = *(const short8*)(&At[(s * 16 + l15) * 140 + kc * 32 + q * 8]);
        short8 Ar = relu8(Ah);
        C1[s] = MFMA16(Ar, w0w[kc], C1[s]);
        C2[s] = MFMA16(Ah, wsw[kc], C2[s]);
      }
    }
#pragma unroll
    for (int s = 0; s < 4; s++)
#pragma unroll
      for (int r = 0; r < 4; r++)
        m2[(s * 16 + q * 4 + r) * 140 + nt * 16 + l15] =
            f32_to_bf16(fmaxf(C1[s][r], 0.f));
    __syncthreads();  // #3: m2 ready; all At reads done
    // phase 2: C2 += m2 @ W1
#pragma unroll
    for (int kc = 0; kc < 4; kc++) {
#pragma unroll
      for (int s = 0; s < 4; s++) {
        short8 Am = *(const short8*)(&m2[(s * 16 + l15) * 140 + kc * 32 + q * 8]);
        C2[s] = MFMA16(Am, w1w[kc], C2[s]);
      }
    }
    if (doPool) {
      float m = -1e30f;
#pragma unroll
      for (int s = 0; s < 4; s++)
#pragma unroll
        for (int r = 0; r < 4; r++) m = fmaxf(m, C2[s][r]);
      m = fmaxf(m, __shfl_xor(m, 16, 64));
      m = fmaxf(m, __shfl_xor(m, 32, 64));
      if (lane < 16) atomicMax(&pool[b * 128 + nt * 16 + lane], f32_key(m));
    }
    // write output into At (At reads finished at #3)
#pragma unroll
    for (int s = 0; s < 4; s++)
#pragma unroll
      for (int r = 0; r < 4; r++)
        At[(s * 16 + q * 4 + r) * 140 + nt * 16 + l15] = f32_to_bf16(C2[s][r]);
    __syncthreads();  // #4: out tile ready
    {
      int destRow = rowBase + r8;
      if (useRank) destRow = rank[destRow];  // sorted scatter (stage 4)
      short8 v0 = *(const short8*)(&At[r8 * 140 + cs8]);
      short8 v1 = *(const short8*)(&At[r8 * 140 + cs8 + 8]);
      *(short8*)(hout + (size_t)destRow * 128 + cs8) = v0;
      *(short8*)(hout + (size_t)destRow * 128 + cs8 + 8) = v1;
    }
  }
}

// ---------------- fold: per-batch effective biases from pool ---------------
__global__ void fold_kernel(const unsigned int* __restrict__ pool,
                            const float* __restrict__ b0s,
                            const float* __restrict__ b1s,
                            const float* __restrict__ w0hi,  // f32, rows 128..255
                            const float* __restrict__ wshi,
                            float* __restrict__ b0e, float* __restrict__ bse) {
  __shared__ float ps[256];
  int tid = threadIdx.x;  // 256
  int b = tid >> 7, j = tid & 127;
  ps[tid] = key_f32(pool[tid]);
  __syncthreads();
  float a0 = b0s[j], a1 = b1s[j];
  for (int ch = 0; ch < 128; ch++) {
    float pv = ps[b * 128 + ch];
    a0 = fmaf(fmaxf(pv, 0.f), w0hi[ch * HD + j], a0);
    a1 = fmaf(pv, wshi[ch * HD + j], a1);
  }
  b0e[b * 128 + j] = a0;
  bse[b * 128 + j] = a1;
}

extern "C" void kernel_launch(void* const* d_in, const int* in_sizes, int n_in,
                              void* d_out, int out_size, void* d_ws,
                              size_t ws_size, hipStream_t stream) {
  const float* p   = (const float*)d_in[0];
  const float* fcw = (const float*)d_in[1];
  const float* fcb = (const float*)d_in[2];
  const float* w0  = (const float*)d_in[3];
  const float* b0  = (const float*)d_in[4];
  const float* w1  = (const float*)d_in[5];
  const float* b1  = (const float*)d_in[6];
  const float* wsc = (const float*)d_in[7];
  float* out = (float*)d_out;

  char* wsp = (char*)d_ws;
  unsigned short* hA = (unsigned short*)wsp;
  unsigned short* hB = hA + (size_t)G_ALL * HD;
  unsigned short* B0t = hB + (size_t)G_ALL * HD;  // [128][256]
  unsigned short* W0t = B0t + 32768;   // [4][128][128]
  unsigned short* W1t = W0t + 65536;   // [5][128][128]
  unsigned short* WSt = W1t + 81920;   // [4][128][128]
  unsigned int* pool = (unsigned int*)(WSt + 65536);  // [4][2][128]
  float* b0e = (float*)(pool + 1024);    // [4][2][128]
  float* bse = b0e + 1024;
  float* Sp  = bse + 1024;               // [3][128]
  float* bsp = Sp + 384;                 // [128]
  int* hist    = (int*)(bsp + 128);      // [2][16384] (becomes cursor)
  int* offsets = hist + 2 * NBINS;       // [2*16384 + 1] (+pad)
  int* rank    = offsets + 2 * NBINS + 4;  // [131072]

  prep_kernel<<<128, 128, 0, stream>>>(fcw, fcb, wsc, Sp, bsp, pool, hist);
  wi_kernel<<<1472, 256, 0, stream>>>(w0, w1, wsc, p, B0t, W0t, W1t, WSt, hist);
  scan_kernel<<<1, 1024, 0, stream>>>(hist, offsets);
  fill_kernel<<<512, 256, 0, stream>>>(p, hist, rank);

  stage0_kernel<<<512, 512, 0, stream>>>(p, fcw, fcb, B0t, W1t,
                                         b0, b1, Sp, bsp, hA, pool);
  unsigned short* hin = hA;
  unsigned short* hout = hB;
  for (int s = 1; s < 5; s++) {
    fold_kernel<<<1, 256, 0, stream>>>(
        pool + (s - 1) * 256, b0 + s * HD, b1 + s * HD,
        w0 + (size_t)(s * 256 + 128) * HD, wsc + (size_t)(s * 256 + 128) * HD,
        b0e + (s - 1) * 256, bse + (s - 1) * 256);
    stageN_kernel<<<512, 512, 0, stream>>>(
        hin, hout, W0t + (s - 1) * 16384, W1t + s * 16384,
        WSt + (s - 1) * 16384, b0e + (s - 1) * 256, bse + (s - 1) * 256,
        pool + s * 256, (s < 4) ? 1 : 0, rank, (s == 4) ? 1 : 0);
    unsigned short* t = hin; hin = hout; hout = t;
  }
  gather_kernel<<<512, 256, 0, stream>>>(hin, offsets, out);
}

// Round 13
// 354.897 us; speedup vs baseline: 1.0145x; 1.0145x over previous
//
#include <hip/hip_runtime.h>
#include <hip/hip_bf16.h>

// LocalResnetPointnet v13: r12 + barrier reduction via buffer choreography.
// stageN: double-buffered At, out-tile into At[b], staging into At[1-b]
//   => 2 syncs/tile (was 4). Store->stage hazard is wave-private (rows tid>>3).
// stage0: out-tile at stride 264 inside x0t region => 3 syncs/tile (was 4).

#define G_ALL 131072   // B*T
#define HD    128
#define NBINS 16384

typedef __attribute__((ext_vector_type(8))) short short8;
typedef __attribute__((ext_vector_type(4))) short short4v;
typedef __attribute__((ext_vector_type(4))) float f32x4;

#define MFMA16(a, b, c) __builtin_amdgcn_mfma_f32_16x16x32_bf16(a, b, c, 0, 0, 0)

__device__ __forceinline__ float bf16_to_f32(unsigned short u) {
  union { unsigned int u; float f; } v; v.u = ((unsigned int)u) << 16; return v.f;
}
__device__ __forceinline__ unsigned short f32_to_bf16(float f) {
  union { float f; unsigned int u; } v; v.f = f;
  unsigned int u = v.u;
  u += 0x7fffu + ((u >> 16) & 1u);   // RNE (no NaNs in this workload)
  return (unsigned short)(u >> 16);
}
// order-preserving float -> uint key for atomicMax
__device__ __forceinline__ unsigned int f32_key(float f) {
  union { float f; unsigned int u; } v; v.f = f;
  return (v.u & 0x80000000u) ? ~v.u : (v.u | 0x80000000u);
}
__device__ __forceinline__ float key_f32(unsigned int k) {
  union { unsigned int u; float f; } v;
  v.u = (k & 0x80000000u) ? (k & 0x7fffffffu) : ~k;
  return v.f;
}
__device__ __forceinline__ int bin_of(float p0, float p2) {
  float x = p0 / 1.101f + 0.5f;
  x = fminf(fmaxf(x, 0.0f), 1.0f - 1e-6f);
  int xi = (int)(x * 128.0f);
  float z = p2 / 1.101f + 0.5f;
  z = fminf(fmaxf(z, 0.0f), 1.0f - 1e-6f);
  int zi = (int)(z * 128.0f);
  return xi + 128 * zi;
}
__device__ __forceinline__ short8 relu8(short8 a) {
  short8 r;
#pragma unroll
  for (int e = 0; e < 8; e++) r[e] = a[e] < 0 ? (short)0 : a[e];
  return r;
}

// ---------------- prep: zero hist/pool; block 0 computes Sp/bsp ------------
__global__ __launch_bounds__(128) void prep_kernel(
    const float* __restrict__ fcw, const float* __restrict__ fcb,
    const float* __restrict__ ws0, float* __restrict__ Sp,
    float* __restrict__ bsp, unsigned int* __restrict__ pool,
    int* __restrict__ hist) {
  int t = blockIdx.x * 128 + threadIdx.x;  // 16384 threads
  hist[t * 2] = 0;
  hist[t * 2 + 1] = 0;
  if (t < 1024) pool[t] = 0u;
  if (blockIdx.x == 0) {
    int j = threadIdx.x;
    for (int d = 0; d < 3; d++) {
      float s = 0.f;
      for (int ch = 0; ch < 256; ch++)
        s = fmaf(fcw[d * 256 + ch], ws0[ch * HD + j], s);
      Sp[d * HD + j] = s;
    }
    float s = 0.f;
    for (int ch = 0; ch < 256; ch++)
      s = fmaf(fcb[ch], ws0[ch * HD + j], s);
    bsp[j] = s;
  }
}

// ---------------- merged: weight transpose/cast + bin histogram ------------
__global__ __launch_bounds__(256) void wi_kernel(
    const float* __restrict__ w0, const float* __restrict__ w1,
    const float* __restrict__ ws, const float* __restrict__ p,
    unsigned short* __restrict__ B0t, unsigned short* __restrict__ W0t,
    unsigned short* __restrict__ W1t, unsigned short* __restrict__ WSt,
    int* __restrict__ hist) {
  int gid = blockIdx.x * 256 + threadIdx.x;
  if (gid >= 245760) {                     // index part: 131072 threads
    int g = gid - 245760;
    int b = g >> 16;
    int idx = bin_of(p[3 * (size_t)g], p[3 * (size_t)g + 2]);
    atomicAdd(&hist[b * NBINS + idx], 1);
    return;
  }
  float v;
  unsigned short* dstp;
  int dst;
  if (gid < 32768) {                       // B0t: [n][k] from w0[0] (256x128)
    int n = gid >> 8, k = gid & 255;
    v = w0[k * 128 + n];
    dstp = B0t; dst = gid;
  } else if (gid < 98304) {                // W0t stages 1..4, rows 0..127
    int i = gid - 32768; int s = i >> 14; int n = (i >> 7) & 127; int k = i & 127;
    v = w0[(size_t)((s + 1) * 256 + k) * 128 + n];
    dstp = W0t; dst = i;
  } else if (gid < 180224) {               // W1t stages 0..4
    int i = gid - 98304; int s = i >> 14; int n = (i >> 7) & 127; int k = i & 127;
    v = w1[(size_t)(s * 128 + k) * 128 + n];
    dstp = W1t; dst = i;
  } else {                                 // WSt stages 1..4, rows 0..127
    int i = gid - 180224; int s = i >> 14; int n = (i >> 7) & 127; int k = i & 127;
    v = ws[(size_t)((s + 1) * 256 + k) * 128 + n];
    dstp = WSt; dst = i;
  }
  dstp[dst] = f32_to_bf16(v);
}

__global__ __launch_bounds__(1024) void scan_kernel(int* __restrict__ hist,
                                                    int* __restrict__ offsets) {
  __shared__ int sd[1024];
  int t = threadIdx.x;
  int vals[32];
  int s = 0;
#pragma unroll
  for (int i = 0; i < 32; i++) { vals[i] = hist[t * 32 + i]; s += vals[i]; }
  sd[t] = s;
  __syncthreads();
  for (int d = 1; d < 1024; d <<= 1) {
    int v = (t >= d) ? sd[t - d] : 0;
    __syncthreads();
    sd[t] += v;
    __syncthreads();
  }
  int run = sd[t] - s;  // exclusive prefix
#pragma unroll
  for (int i = 0; i < 32; i++) {
    offsets[t * 32 + i] = run;
    hist[t * 32 + i] = run;  // cursor copy (in-place)
    run += vals[i];
  }
  if (t == 1023) offsets[32768] = run;  // sentinel = G_ALL
}

__global__ __launch_bounds__(256) void fill_kernel(const float* __restrict__ p,
                                                   int* __restrict__ cursor,
                                                   int* __restrict__ rank) {
  int g = blockIdx.x * 256 + threadIdx.x;
  int b = g >> 16;
  int idx = bin_of(p[3 * (size_t)g], p[3 * (size_t)g + 2]);
  int pos = atomicAdd(&cursor[b * NBINS + idx], 1);
  rank[g] = pos;
}

// gather + mean over SORTED rows: block = 64 bins, rows sequential, no
// indirection. Register accumulate -> LDS transpose -> coalesced stores.
__global__ __launch_bounds__(256) void gather_kernel(
    const unsigned short* __restrict__ cS, const int* __restrict__ offsets,
    float* __restrict__ out) {
  __shared__ float acc[129 * 65];  // [ch 0..127 | cnt row 128][bin 0..63]
  const int tid = threadIdx.x;
  const int wave = tid >> 6, lane = tid & 63;
  const int B0 = blockIdx.x * 64;          // global bin base (0..32767)
  const int b = B0 >> 14;

  for (int bi = 0; bi < 16; bi++) {
    const int binL = wave * 16 + bi;
    const int B = B0 + binL;
    const int st = offsets[B], en = offsets[B + 1];
    float a0 = 0.f, a1 = 0.f;
    int k = st;
    for (; k + 2 <= en; k += 2) {
      unsigned int u0 = *(const unsigned int*)(cS + (size_t)k * HD + lane * 2);
      unsigned int u1 = *(const unsigned int*)(cS + (size_t)(k + 1) * HD + lane * 2);
      a0 += bf16_to_f32((unsigned short)(u0 & 0xffffu));
      a1 += bf16_to_f32((unsigned short)(u0 >> 16));
      a0 += bf16_to_f32((unsigned short)(u1 & 0xffffu));
      a1 += bf16_to_f32((unsigned short)(u1 >> 16));
    }
    if (k < en) {
      unsigned int u = *(const unsigned int*)(cS + (size_t)k * HD + lane * 2);
      a0 += bf16_to_f32((unsigned short)(u & 0xffffu));
      a1 += bf16_to_f32((unsigned short)(u >> 16));
    }
    acc[(2 * lane) * 65 + binL] = a0;
    acc[(2 * lane + 1) * 65 + binL] = a1;
    if (lane == 0) acc[128 * 65 + binL] = (float)(en - st);
  }
  __syncthreads();

  const size_t outBase = (size_t)b * HD * NBINS + (size_t)(B0 & (NBINS - 1));
  const float cnt = fmaxf(acc[128 * 65 + lane], 1.0f);
#pragma unroll
  for (int c2 = 0; c2 < 32; c2++) {
    int ch = wave * 32 + c2;
    out[outBase + (size_t)ch * NBINS + lane] = acc[ch * 65 + lane] / cnt;
  }
}

// ---------------- stage 0: fc_pos + block0 (weight-stationary MFMA) --------
// 8 waves; wave = nt (16 output ch). 512 blocks x 4 tiles of 64 rows.
// 3 syncs/tile: out-tile lives in x0t region at stride 264 (row-private store).
__global__ __launch_bounds__(512, 4) void stage0_kernel(
    const float* __restrict__ p, const float* __restrict__ fcw,
    const float* __restrict__ fcb,
    const unsigned short* __restrict__ B0t,
    const unsigned short* __restrict__ W1t,
    const float* __restrict__ b0, const float* __restrict__ b1,
    const float* __restrict__ Sp, const float* __restrict__ bsp,
    unsigned short* __restrict__ hout, unsigned int* __restrict__ pool) {
  __shared__ float fcL[1024];                // fcw (768) + fcb (256)
  __shared__ float ptL[64 * 5];              // stride 5: conflict-free q-reads
  __shared__ unsigned short x0t[64 * 264];   // K=256 relu tile; out tile (stride 264)
  __shared__ unsigned short m2[64 * 140];
  const int tid = threadIdx.x;
  const int lane = tid & 63;
  const int q = lane >> 4, l15 = lane & 15;
  const int nt = tid >> 6;                   // wave id = output-ch tile
  const int b = blockIdx.x >> 8;
  const int wrow = nt * 16 + l15;
  const int row8 = tid >> 3, c4 = (tid & 7) * 4, cs8 = (tid & 7) * 16;

  // weights -> registers (once per kernel): 8 + 4 short8 = 48 VGPRs
  short8 b0w[8], w1w[4];
#pragma unroll
  for (int kc = 0; kc < 8; kc++)
    b0w[kc] = *(const short8*)(B0t + (size_t)wrow * 256 + kc * 32 + q * 8);
#pragma unroll
  for (int kc = 0; kc < 4; kc++)
    w1w[kc] = *(const short8*)(W1t + (size_t)wrow * 128 + kc * 32 + q * 8);
  const float bias1 = b0[wrow];
  const float bias2 = bsp[wrow] + b1[wrow];
  const float sp0 = Sp[wrow], sp1 = Sp[128 + wrow], sp2 = Sp[256 + wrow];

  for (int k = tid; k < 1024; k += 512)
    fcL[k] = (k < 768) ? fcw[k] : fcb[k - 768];

  // prefetch tile 0's p
  float pn0, pn1, pn2, pl = 0.f;
  {
    const int rb = blockIdx.x * 256;
    const float* pr = p + (size_t)(rb + row8) * 3;
    pn0 = pr[0]; pn1 = pr[1]; pn2 = pr[2];
    if (tid < 192) pl = p[(size_t)rb * 3 + tid];
  }
  __syncthreads();  // fcL ready

  for (int it = 0; it < 4; it++) {
    const int rowBase = blockIdx.x * 256 + it * 64;
    // fc_pos from prefetched regs -> x0t (rows row8: wave-private, follows
    // this wave's own store of the previous out-tile; no barrier needed)
    if (tid < 192) ptL[(tid / 3) * 5 + (tid % 3)] = pl;
#pragma unroll
    for (int cc = 0; cc < 8; cc++) {
      int chb = c4 + cc * 32;
      short4v v;
#pragma unroll
      for (int j = 0; j < 4; j++) {
        int ch = chb + j;
        float x = fcL[768 + ch] + pn0 * fcL[ch] + pn1 * fcL[256 + ch] +
                  pn2 * fcL[512 + ch];
        v[j] = (short)f32_to_bf16(fmaxf(x, 0.f));
      }
      *(short4v*)(&x0t[row8 * 264 + chb]) = v;
    }
    if (it < 3) {  // prefetch next tile's p
      const int rb = rowBase + 64;
      const float* pr = p + (size_t)(rb + row8) * 3;
      pn0 = pr[0]; pn1 = pr[1]; pn2 = pr[2];
      if (tid < 192) pl = p[(size_t)rb * 3 + tid];
    }
    __syncthreads();  // A: x0t + ptL ready
    // phase 1: net = relu(x0) @ W0[0] + b0[0]  (K=256)
    f32x4 C1[4];
#pragma unroll
    for (int s = 0; s < 4; s++) C1[s] = (f32x4){bias1, bias1, bias1, bias1};
#pragma unroll
    for (int kc = 0; kc < 8; kc++) {
#pragma unroll
      for (int s = 0; s < 4; s++) {
        short8 Ar = *(const short8*)(&x0t[(s * 16 + l15) * 264 + kc * 32 + q * 8]);
        C1[s] = MFMA16(Ar, b0w[kc], C1[s]);
      }
    }
#pragma unroll
    for (int s = 0; s < 4; s++)
#pragma unroll
      for (int r = 0; r < 4; r++)
        m2[(s * 16 + q * 4 + r) * 140 + nt * 16 + l15] =
            f32_to_bf16(fmaxf(C1[s][r], 0.f));
    __syncthreads();  // B: m2 ready; x0t phase-1 reads done -> out region
    // phase 2: h = m2 @ W1[0] + (p @ Sp + bsp + b1[0])
    f32x4 C2[4];
#pragma unroll
    for (int s = 0; s < 4; s++)
#pragma unroll
      for (int r = 0; r < 4; r++) {
        int row = s * 16 + q * 4 + r;
        C2[s][r] = bias2 + ptL[row * 5] * sp0 + ptL[row * 5 + 1] * sp1 +
                   ptL[row * 5 + 2] * sp2;
      }
#pragma unroll
    for (int kc = 0; kc < 4; kc++) {
#pragma unroll
      for (int s = 0; s < 4; s++) {
        short8 Am = *(const short8*)(&m2[(s * 16 + l15) * 140 + kc * 32 + q * 8]);
        C2[s] = MFMA16(Am, w1w[kc], C2[s]);
      }
    }
#pragma unroll
    for (int s = 0; s < 4; s++)
#pragma unroll
      for (int r = 0; r < 4; r++)
        x0t[(s * 16 + q * 4 + r) * 264 + nt * 16 + l15] = f32_to_bf16(C2[s][r]);
    {
      float m = -1e30f;
#pragma unroll
      for (int s = 0; s < 4; s++)
#pragma unroll
        for (int r = 0; r < 4; r++) m = fmaxf(m, C2[s][r]);
      m = fmaxf(m, __shfl_xor(m, 16, 64));
      m = fmaxf(m, __shfl_xor(m, 32, 64));
      if (lane < 16) atomicMax(&pool[b * 128 + nt * 16 + lane], f32_key(m));
    }
    __syncthreads();  // C: out tile ready
    {
      short8 v0 = *(const short8*)(&x0t[row8 * 264 + cs8]);
      short8 v1 = *(const short8*)(&x0t[row8 * 264 + cs8 + 8]);
      *(short8*)(hout + (size_t)(rowBase + row8) * 128 + cs8) = v0;
      *(short8*)(hout + (size_t)(rowBase + row8) * 128 + cs8 + 8) = v1;
    }
  }
}

// ---------------- stages 1..4 (weight-stationary, 2 syncs/tile) ------------
// 8 waves; wave = nt. 512 blocks x 4 tiles of 64 rows. WS fused in phase 1.
// Double-buffered At: out-tile into At[b], next H staged into At[1-b].
__global__ __launch_bounds__(512, 4) void stageN_kernel(
    const unsigned short* __restrict__ hin, unsigned short* __restrict__ hout,
    const unsigned short* __restrict__ W0t,
    const unsigned short* __restrict__ W1t,
    const unsigned short* __restrict__ WSt,
    const float* __restrict__ b0e, const float* __restrict__ bse,
    unsigned int* __restrict__ pool, int doPool,
    const int* __restrict__ rank, int useRank) {
  __shared__ unsigned short At[2][64 * 140];  // H / out tiles (ping-pong)
  __shared__ unsigned short m2[64 * 140];     // relu(net)
  const int tid = threadIdx.x;
  const int lane = tid & 63;
  const int q = lane >> 4, l15 = lane & 15;
  const int nt = tid >> 6;
  const int b = blockIdx.x >> 8;
  const int wrow = nt * 16 + l15;

  // 12 short8 = 48 VGPRs of weights
  short8 w0w[4], w1w[4], wsw[4];
#pragma unroll
  for (int kc = 0; kc < 4; kc++) {
    w0w[kc] = *(const short8*)(W0t + (size_t)wrow * 128 + kc * 32 + q * 8);
    w1w[kc] = *(const short8*)(W1t + (size_t)wrow * 128 + kc * 32 + q * 8);
    wsw[kc] = *(const short8*)(WSt + (size_t)wrow * 128 + kc * 32 + q * 8);
  }
  const float bias1 = b0e[b * 128 + wrow];
  const float bias2 = bse[b * 128 + wrow];
  const int r8 = tid >> 3, cs8 = (tid & 7) * 16;

  // prologue: stage tile 0 into At[0]; prefetch tile 1 regs
  short8 n0, n1;
  {
    const size_t gb = ((size_t)blockIdx.x * 256 + r8) * 128 + cs8;
    short8 v0 = *(const short8*)(hin + gb);
    short8 v1 = *(const short8*)(hin + gb + 8);
    *(short8*)(&At[0][r8 * 140 + cs8]) = v0;
    *(short8*)(&At[0][r8 * 140 + cs8 + 8]) = v1;
    const size_t gb1 = gb + 64 * 128;
    n0 = *(const short8*)(hin + gb1);
    n1 = *(const short8*)(hin + gb1 + 8);
  }
  __syncthreads();  // At[0] ready

  for (int it = 0; it < 4; it++) {
    const int cur = it & 1;
    const int rowBase = blockIdx.x * 256 + it * 64;
    // phase 1: C1 = relu(H)@W0 + b0e ; C2 = H@WS + bse (shortcut fused)
    f32x4 C1[4], C2[4];
#pragma unroll
    for (int s = 0; s < 4; s++) {
      C1[s] = (f32x4){bias1, bias1, bias1, bias1};
      C2[s] = (f32x4){bias2, bias2, bias2, bias2};
    }
#pragma unroll
    for (int kc = 0; kc < 4; kc++) {
#pragma unroll
      for (int s = 0; s < 4; s++) {
        short8 Ah = *(const short8*)(&At[cur][(s * 16 + l15) * 140 + kc * 32 + q * 8]);
        short8 Ar = relu8(Ah);
        C1[s] = MFMA16(Ar, w0w[kc], C1[s]);
        C2[s] = MFMA16(Ah, wsw[kc], C2[s]);
      }
    }
#pragma unroll
    for (int s = 0; s < 4; s++)
#pragma unroll
      for (int r = 0; r < 4; r++)
        m2[(s * 16 + q * 4 + r) * 140 + nt * 16 + l15] =
            f32_to_bf16(fmaxf(C1[s][r], 0.f));
    // stage next tile's H into the other buffer (rows r8: wave-private;
    // this wave's store of the previous out-tile from At[1-cur] already
    // executed in program order)
    if (it < 3) {
      *(short8*)(&At[1 - cur][r8 * 140 + cs8]) = n0;
      *(short8*)(&At[1 - cur][r8 * 140 + cs8 + 8]) = n1;
    }
    if (it < 2) {  // prefetch tile it+2
      const size_t gb = ((size_t)(rowBase + 128) + r8) * 128 + cs8;
      n0 = *(const short8*)(hin + gb);
      n1 = *(const short8*)(hin + gb + 8);
    }
    __syncthreads();  // A: m2 ready (+ staging done); At[cur] reads done
    // phase 2: C2 += m2 @ W1
#pragma unroll
    for (int kc = 0; kc < 4; kc++) {
#pragma unroll
      for (int s = 0; s < 4; s++) {
        short8 Am = *(const short8*)(&m2[(s * 16 + l15) * 140 + kc * 32 + q * 8]);
        C2[s] = MFMA16(Am, w1w[kc], C2[s]);
      }
    }
    if (doPool) {
      float m = -1e30f;
#pragma unroll
      for (int s = 0; s < 4; s++)
#pragma unroll
        for (int r = 0; r < 4; r++) m = fmaxf(m, C2[s][r]);
      m = fmaxf(m, __shfl_xor(m, 16, 64));
      m = fmaxf(m, __shfl_xor(m, 32, 64));
      if (lane < 16) atomicMax(&pool[b * 128 + nt * 16 + lane], f32_key(m));
    }
    // out-tile into At[cur] (phase-1 reads of it completed at sync A)
#pragma unroll
    for (int s = 0; s < 4; s++)
#pragma unroll
      for (int r = 0; r < 4; r++)
        At[cur][(s * 16 + q * 4 + r) * 140 + nt * 16 + l15] = f32_to_bf16(C2[s][r]);
    __syncthreads();  // B: out tile ready
    {
      int destRow = rowBase + r8;
      if (useRank) destRow = rank[destRow];  // sorted scatter (stage 4)
      short8 v0 = *(const short8*)(&At[cur][r8 * 140 + cs8]);
      short8 v1 = *(const short8*)(&At[cur][r8 * 140 + cs8 + 8]);
      *(short8*)(hout + (size_t)destRow * 128 + cs8) = v0;
      *(short8*)(hout + (size_t)destRow * 128 + cs8 + 8) = v1;
    }
  }
}

// ---------------- fold: per-batch effective biases from pool ---------------
__global__ void fold_kernel(const unsigned int* __restrict__ pool,
                            const float* __restrict__ b0s,
                            const float* __restrict__ b1s,
                            const float* __restrict__ w0hi,  // f32, rows 128..255
                            const float* __restrict__ wshi,
                            float* __restrict__ b0e, float* __restrict__ bse) {
  __shared__ float ps[256];
  int tid = threadIdx.x;  // 256
  int b = tid >> 7, j = tid & 127;
  ps[tid] = key_f32(pool[tid]);
  __syncthreads();
  float a0 = b0s[j], a1 = b1s[j];
  for (int ch = 0; ch < 128; ch++) {
    float pv = ps[b * 128 + ch];
    a0 = fmaf(fmaxf(pv, 0.f), w0hi[ch * HD + j], a0);
    a1 = fmaf(pv, wshi[ch * HD + j], a1);
  }
  b0e[b * 128 + j] = a0;
  bse[b * 128 + j] = a1;
}

extern "C" void kernel_launch(void* const* d_in, const int* in_sizes, int n_in,
                              void* d_out, int out_size, void* d_ws,
                              size_t ws_size, hipStream_t stream) {
  const float* p   = (const float*)d_in[0];
  const float* fcw = (const float*)d_in[1];
  const float* fcb = (const float*)d_in[2];
  const float* w0  = (const float*)d_in[3];
  const float* b0  = (const float*)d_in[4];
  const float* w1  = (const float*)d_in[5];
  const float* b1  = (const float*)d_in[6];
  const float* wsc = (const float*)d_in[7];
  float* out = (float*)d_out;

  char* wsp = (char*)d_ws;
  unsigned short* hA = (unsigned short*)wsp;
  unsigned short* hB = hA + (size_t)G_ALL * HD;
  unsigned short* B0t = hB + (size_t)G_ALL * HD;  // [128][256]
  unsigned short* W0t = B0t + 32768;   // [4][128][128]
  unsigned short* W1t = W0t + 65536;   // [5][128][128]
  unsigned short* WSt = W1t + 81920;   // [4][128][128]
  unsigned int* pool = (unsigned int*)(WSt + 65536);  // [4][2][128]
  float* b0e = (float*)(pool + 1024);    // [4][2][128]
  float* bse = b0e + 1024;
  float* Sp  = bse + 1024;               // [3][128]
  float* bsp = Sp + 384;                 // [128]
  int* hist    = (int*)(bsp + 128);      // [2][16384] (becomes cursor)
  int* offsets = hist + 2 * NBINS;       // [2*16384 + 1] (+pad)
  int* rank    = offsets + 2 * NBINS + 4;  // [131072]

  prep_kernel<<<128, 128, 0, stream>>>(fcw, fcb, wsc, Sp, bsp, pool, hist);
  wi_kernel<<<1472, 256, 0, stream>>>(w0, w1, wsc, p, B0t, W0t, W1t, WSt, hist);
  scan_kernel<<<1, 1024, 0, stream>>>(hist, offsets);
  fill_kernel<<<512, 256, 0, stream>>>(p, hist, rank);

  stage0_kernel<<<512, 512, 0, stream>>>(p, fcw, fcb, B0t, W1t,
                                         b0, b1, Sp, bsp, hA, pool);
  unsigned short* hin = hA;
  unsigned short* hout = hB;
  for (int s = 1; s < 5; s++) {
    fold_kernel<<<1, 256, 0, stream>>>(
        pool + (s - 1) * 256, b0 + s * HD, b1 + s * HD,
        w0 + (size_t)(s * 256 + 128) * HD, wsc + (size_t)(s * 256 + 128) * HD,
        b0e + (s - 1) * 256, bse + (s - 1) * 256);
    stageN_kernel<<<512, 512, 0, stream>>>(
        hin, hout, W0t + (s - 1) * 16384, W1t + s * 16384,
        WSt + (s - 1) * 16384, b0e + (s - 1) * 256, bse + (s - 1) * 256,
        pool + s * 256, (s < 4) ? 1 : 0, rank, (s == 4) ? 1 : 0);
    unsigned short* t = hin; hin = hout; hout = t;
  }
  gather_kernel<<<512, 256, 0, stream>>>(hin, offsets, out);
}